// Round 1
// baseline (650.210 us; speedup 1.0000x reference)
//
#include <hip/hip_runtime.h>
#include <hip/hip_bf16.h>
#include <cstdint>

// Problem constants
#define BSZ   4
#define TLEN  4096
#define DM    1024
#define NS    256
#define DFF   2736
#define DFFP  2816        // padded to multiple of 128
#define NCHUNK 64
#define CLEN   64         // TLEN / NCHUNK

typedef __attribute__((ext_vector_type(8))) short bf16x8;
typedef __attribute__((ext_vector_type(4))) float f32x4;

__device__ __forceinline__ float bf2f(ushort u) {
  union { unsigned int i; float f; } v; v.i = ((unsigned int)u) << 16; return v.f;
}
__device__ __forceinline__ ushort f2bf(float f) {
  union { float f; unsigned int i; } v; v.f = f;
  unsigned int r = v.i + 0x7FFFu + ((v.i >> 16) & 1u);
  return (ushort)(r >> 16);
}
__device__ __forceinline__ void gload16(const ushort* g, ushort* l) {
  __builtin_amdgcn_global_load_lds((const __attribute__((address_space(1))) void*)g,
                                   (__attribute__((address_space(3))) void*)l, 16, 0, 0);
}

// ---------------- weight convert + pad to bf16 ----------------
__global__ void convert_pad(const float* __restrict__ src, ushort* __restrict__ dst,
                            int srcR, int srcC, int dstR, int dstC) {
  long total = (long)dstR * dstC / 4;
  for (long q = (long)blockIdx.x * blockDim.x + threadIdx.x; q < total;
       q += (long)gridDim.x * blockDim.x) {
    long e = q * 4;
    int r = (int)(e / dstC);
    int c = (int)(e % dstC);
    ushort4 o;
    float v0 = (r < srcR && c + 0 < srcC) ? src[(long)r * srcC + c + 0] : 0.f;
    float v1 = (r < srcR && c + 1 < srcC) ? src[(long)r * srcC + c + 1] : 0.f;
    float v2 = (r < srcR && c + 2 < srcC) ? src[(long)r * srcC + c + 2] : 0.f;
    float v3 = (r < srcR && c + 3 < srcC) ? src[(long)r * srcC + c + 3] : 0.f;
    o.x = f2bf(v0); o.y = f2bf(v1); o.z = f2bf(v2); o.w = f2bf(v3);
    *(ushort4*)(dst + e) = o;
  }
}

// ---------------- RMSNorm (f32 in -> bf16 out) ----------------
__global__ __launch_bounds__(256) void rmsnorm_bf16(const float* __restrict__ x,
                                                    const float* __restrict__ w,
                                                    ushort* __restrict__ out) {
  long row = blockIdx.x;
  int tid = threadIdx.x;
  const float4* xr = (const float4*)(x + row * DM);
  float4 v = xr[tid];
  float ss = v.x * v.x + v.y * v.y + v.z * v.z + v.w * v.w;
#pragma unroll
  for (int m = 32; m >= 1; m >>= 1) ss += __shfl_xor(ss, m);
  __shared__ float red[4];
  if ((tid & 63) == 0) red[tid >> 6] = ss;
  __syncthreads();
  float tot = red[0] + red[1] + red[2] + red[3];
  float inv = rsqrtf(tot * (1.0f / DM) + 1e-6f);
  float4 wv = ((const float4*)w)[tid];
  ushort4 o;
  o.x = f2bf(v.x * inv * wv.x);
  o.y = f2bf(v.y * inv * wv.y);
  o.z = f2bf(v.z * inv * wv.z);
  o.w = f2bf(v.w * inv * wv.w);
  ((ushort4*)(out + row * DM))[tid] = o;
}

// ---------------- scan phase A: local per-chunk scan (in place) ----------------
__global__ __launch_bounds__(256) void scan_local(float* __restrict__ Bu,
                                                  float* __restrict__ E,
                                                  const float* __restrict__ loglam) {
  int bc = blockIdx.x;
  int b = bc / NCHUNK, c = bc % NCHUNK;
  int n = threadIdx.x;
  float lam = 1.f / (1.f + __expf(-loglam[n]));
  float h = 0.f;
  long base = ((long)b * TLEN + (long)c * CLEN) * NS + n;
#pragma unroll 4
  for (int t = 0; t < CLEN; ++t) {
    long idx = base + (long)t * NS;
    h = lam * h + Bu[idx];
    Bu[idx] = h;
  }
  E[((long)b * NCHUNK + c) * NS + n] = h;
}

// ---------------- scan phase B: chunk-carry combine ----------------
__global__ __launch_bounds__(1024) void scan_carry(const float* __restrict__ E,
                                                   float* __restrict__ C,
                                                   const float* __restrict__ loglam) {
  int tid = threadIdx.x;           // 0..1023
  int b = tid >> 8, n = tid & 255;
  float lam = 1.f / (1.f + __expf(-loglam[n]));
  float lamL = lam;
#pragma unroll
  for (int i = 0; i < 6; ++i) lamL *= lamL;   // lam^64
  float carry = 0.f;
  for (int c = 0; c < NCHUNK; ++c) {
    long idx = ((long)b * NCHUNK + c) * NS + n;
    C[idx] = carry;
    carry = lamL * carry + E[idx];
  }
}

// ---------------- scan phase C: add carry, emit bf16 hs ----------------
__global__ __launch_bounds__(256) void scan_fix(const float* __restrict__ local,
                                                const float* __restrict__ Carry,
                                                const float* __restrict__ loglam,
                                                ushort* __restrict__ hsb) {
  int bc = blockIdx.x;
  int b = bc / NCHUNK, c = bc % NCHUNK;
  int n = threadIdx.x;
  float lam = 1.f / (1.f + __expf(-loglam[n]));
  float p = Carry[((long)b * NCHUNK + c) * NS + n];
  long base = ((long)b * TLEN + (long)c * CLEN) * NS + n;
#pragma unroll 4
  for (int t = 0; t < CLEN; ++t) {
    p *= lam;
    long idx = base + (long)t * NS;
    hsb[idx] = f2bf(local[idx] + p);
  }
}

// ---------------- bf16 NT GEMM, 128x128x32, m97 structure ----------------
// A [M,K] bf16 row-major; B [N,K] bf16 row-major (i.e. op is A * B^T).
// EPI: 0 = store f32
//      1 = out = acc + x + Dskip*u   (residual-1, N==DM)
//      2 = dual-B: gv = silu(accB0) * accB1 -> bf16
//      3 = outF[idx] += acc           (residual-2 in place)
template <int EPI>
__global__ __launch_bounds__(256, 2) void gemm_bt(
    const ushort* __restrict__ A, const ushort* __restrict__ B0, const ushort* __restrict__ B1,
    float* __restrict__ outF, ushort* __restrict__ outU,
    const float* __restrict__ xin, const float* __restrict__ dskip,
    const ushort* __restrict__ uin, int M, int N, int K) {
  constexpr bool DUAL = (EPI == 2);
  __shared__ ushort sA[128 * 32];
  __shared__ ushort sB[128 * 32];
  __shared__ ushort sB1[DUAL ? 128 * 32 : 4];

  int tid = threadIdx.x;
  int lane = tid & 63;
  int wid = tid >> 6;
  int nbx = N >> 7;
  int by = blockIdx.x / nbx;
  int bx = blockIdx.x - by * nbx;
  long brow = (long)by << 7;
  long bcol = (long)bx << 7;

  // staging addresses: thread t stages 16B at tile byte q*4096 + t*16
  int srow = tid >> 2;           // 0..63
  int scol = (tid & 3) << 3;     // element col: 0,8,16,24
  const ushort* gA = A + (brow + srow) * (long)K + scol;
  const ushort* gB = B0 + (bcol + srow) * (long)K + scol;
  const ushort* gB1p = nullptr;
  if constexpr (DUAL) gB1p = B1 + (bcol + srow) * (long)K + scol;
  ushort* lA = sA + (wid << 9);   // wave-uniform base, +1024B per wave
  ushort* lB = sB + (wid << 9);
  ushort* lB1 = sB1 + (wid << 9);

  int wr = wid >> 1, wc = wid & 1;            // 2x2 waves, each 64x64
  int fr = lane & 15;
  int fk = (lane >> 4) << 3;

  f32x4 acc0[4][4];
  f32x4 acc1[DUAL ? 4 : 1][DUAL ? 4 : 1];
#pragma unroll
  for (int i = 0; i < 4; ++i)
#pragma unroll
    for (int j = 0; j < 4; ++j) {
      acc0[i][j] = (f32x4)0.f;
      if constexpr (DUAL) acc1[i][j] = (f32x4)0.f;
    }

  long rowq = 64 * (long)K;
  for (int kt = 0; kt < K; kt += 32) {
    __syncthreads();
    gload16(gA + kt, lA);
    gload16(gA + kt + rowq, lA + 2048);
    gload16(gB + kt, lB);
    gload16(gB + kt + rowq, lB + 2048);
    if constexpr (DUAL) {
      gload16(gB1p + kt, lB1);
      gload16(gB1p + kt + rowq, lB1 + 2048);
    }
    __syncthreads();

    bf16x8 a[4], b[4], b2[4];
#pragma unroll
    for (int i = 0; i < 4; ++i)
      a[i] = *(const bf16x8*)(sA + ((wr * 64 + i * 16 + fr) * 32 + fk));
#pragma unroll
    for (int j = 0; j < 4; ++j) {
      b[j] = *(const bf16x8*)(sB + ((wc * 64 + j * 16 + fr) * 32 + fk));
      if constexpr (DUAL)
        b2[j] = *(const bf16x8*)(sB1 + ((wc * 64 + j * 16 + fr) * 32 + fk));
    }
#pragma unroll
    for (int i = 0; i < 4; ++i)
#pragma unroll
      for (int j = 0; j < 4; ++j) {
        acc0[i][j] = __builtin_amdgcn_mfma_f32_16x16x32_bf16(a[i], b[j], acc0[i][j], 0, 0, 0);
        if constexpr (DUAL)
          acc1[i][j] = __builtin_amdgcn_mfma_f32_16x16x32_bf16(a[i], b2[j], acc1[i][j], 0, 0, 0);
      }
  }

  // epilogue: C/D layout col = lane&15, row = (lane>>4)*4 + reg
#pragma unroll
  for (int i = 0; i < 4; ++i) {
    int rowb = wr * 64 + i * 16 + ((lane >> 4) << 2);
#pragma unroll
    for (int j = 0; j < 4; ++j) {
      long gcol = bcol + wc * 64 + j * 16 + fr;
#pragma unroll
      for (int r = 0; r < 4; ++r) {
        long grow = brow + rowb + r;
        long idx = grow * N + gcol;
        float v = acc0[i][j][r];
        if constexpr (EPI == 0) {
          outF[idx] = v;
        } else if constexpr (EPI == 1) {
          outF[idx] = v + xin[idx] + dskip[gcol] * bf2f(uin[idx]);
        } else if constexpr (EPI == 2) {
          float s = v / (1.f + __expf(-v));       // silu(gate)
          outU[idx] = f2bf(s * acc1[i][j][r]);
        } else {
          outF[idx] += v;
        }
      }
    }
  }
}

// ---------------- launch ----------------
extern "C" void kernel_launch(void* const* d_in, const int* in_sizes, int n_in,
                              void* d_out, int out_size, void* d_ws, size_t ws_size,
                              hipStream_t stream) {
  const float* x      = (const float*)d_in[0];
  const float* loglam = (const float*)d_in[1];
  const float* B_w    = (const float*)d_in[2];
  const float* C_w    = (const float*)d_in[3];
  const float* D_skip = (const float*)d_in[4];
  const float* ssm_w  = (const float*)d_in[5];
  const float* ffn_w  = (const float*)d_in[6];
  const float* w1     = (const float*)d_in[7];
  const float* w2     = (const float*)d_in[8];
  const float* w3     = (const float*)d_in[9];
  float* out = (float*)d_out;

  char* ws = (char*)d_ws;
  ushort* u_bf  = (ushort*)(ws + 0);           // 33554432 B (later reused as z)
  float*  Bu    = (float*) (ws + 33554432);    // 16777216 (local scan in place)
  ushort* hs_bf = (ushort*)(ws + 50331648);    // 8388608
  float*  E     = (float*) (ws + 58720256);    // 262144
  float*  Carry = (float*) (ws + 58982400);    // 262144
  ushort* wB    = (ushort*)(ws + 59244544);    // 524288
  ushort* wC    = (ushort*)(ws + 59768832);    // 524288
  ushort* w1p   = (ushort*)(ws + 60293120);    // 5767168
  ushort* w3p   = (ushort*)(ws + 66060288);    // 5767168
  ushort* w2p   = (ushort*)(ws + 71827456);    // 5767168
  ushort* gv    = (ushort*)(ws + 77594624);    // 92274688  -> total 169869312

  auto cvb = [](long elems) {
    long q = elems / 4;
    long b = (q + 255) / 256;
    return (int)(b > 4096 ? 4096 : b);
  };

  // weight conversion (f32 -> bf16, padded)
  convert_pad<<<cvb(256L * 1024), 256, 0, stream>>>(B_w, wB, 256, 1024, 256, 1024);
  convert_pad<<<cvb(1024L * 256), 256, 0, stream>>>(C_w, wC, 1024, 256, 1024, 256);
  convert_pad<<<cvb((long)DFFP * 1024), 256, 0, stream>>>(w1, w1p, DFF, 1024, DFFP, 1024);
  convert_pad<<<cvb((long)DFFP * 1024), 256, 0, stream>>>(w3, w3p, DFF, 1024, DFFP, 1024);
  convert_pad<<<cvb(1024L * DFFP), 256, 0, stream>>>(w2, w2p, 1024, DFF, 1024, DFFP);

  // SSM branch
  rmsnorm_bf16<<<BSZ * TLEN, 256, 0, stream>>>(x, ssm_w, u_bf);
  gemm_bt<0><<<(16384 / 128) * (NS / 128), 256, 0, stream>>>(
      u_bf, wB, nullptr, Bu, nullptr, nullptr, nullptr, nullptr, 16384, NS, DM);
  scan_local<<<BSZ * NCHUNK, 256, 0, stream>>>(Bu, E, loglam);
  scan_carry<<<1, 1024, 0, stream>>>(E, Carry, loglam);
  scan_fix<<<BSZ * NCHUNK, 256, 0, stream>>>(Bu, Carry, loglam, hs_bf);
  gemm_bt<1><<<(16384 / 128) * (DM / 128), 256, 0, stream>>>(
      hs_bf, wC, nullptr, out, nullptr, x, D_skip, u_bf, 16384, DM, NS);

  // FFN branch
  rmsnorm_bf16<<<BSZ * TLEN, 256, 0, stream>>>(out, ffn_w, u_bf);  // z reuses u buffer
  gemm_bt<2><<<(16384 / 128) * (DFFP / 128), 256, 0, stream>>>(
      u_bf, w1p, w3p, nullptr, gv, nullptr, nullptr, nullptr, 16384, DFFP, DM);
  gemm_bt<3><<<(16384 / 128) * (DM / 128), 256, 0, stream>>>(
      gv, w2p, nullptr, out, nullptr, nullptr, nullptr, nullptr, 16384, DM, DFFP);
}

// Round 2
// 622.624 us; speedup vs baseline: 1.0443x; 1.0443x over previous
//
#include <hip/hip_runtime.h>
#include <hip/hip_bf16.h>
#include <cstdint>

// Problem constants
#define BSZ   4
#define TLEN  4096
#define DM    1024
#define NS    256
#define DFF   2736
#define DFFP  2816        // padded to multiple of 128
#define NPK   5632        // interleaved w1/w3 rows (2*DFFP)
#define NCHUNK 64
#define CLEN   64         // TLEN / NCHUNK

typedef __attribute__((ext_vector_type(8))) short bf16x8;
typedef __attribute__((ext_vector_type(4))) float f32x4;

__device__ __forceinline__ float bf2f(ushort u) {
  union { unsigned int i; float f; } v; v.i = ((unsigned int)u) << 16; return v.f;
}
__device__ __forceinline__ ushort f2bf(float f) {
  union { float f; unsigned int i; } v; v.f = f;
  unsigned int r = v.i + 0x7FFFu + ((v.i >> 16) & 1u);
  return (ushort)(r >> 16);
}
__device__ __forceinline__ void gload16(const ushort* g, ushort* l) {
  __builtin_amdgcn_global_load_lds((const __attribute__((address_space(1))) void*)g,
                                   (__attribute__((address_space(3))) void*)l, 16, 0, 0);
}

// ---------------- weight convert + pad to bf16 ----------------
__global__ void convert_pad(const float* __restrict__ src, ushort* __restrict__ dst,
                            int srcR, int srcC, int dstR, int dstC) {
  long total = (long)dstR * dstC / 4;
  for (long q = (long)blockIdx.x * blockDim.x + threadIdx.x; q < total;
       q += (long)gridDim.x * blockDim.x) {
    long e = q * 4;
    int r = (int)(e / dstC);
    int c = (int)(e % dstC);
    ushort4 o;
    float v0 = (r < srcR && c + 0 < srcC) ? src[(long)r * srcC + c + 0] : 0.f;
    float v1 = (r < srcR && c + 1 < srcC) ? src[(long)r * srcC + c + 1] : 0.f;
    float v2 = (r < srcR && c + 2 < srcC) ? src[(long)r * srcC + c + 2] : 0.f;
    float v3 = (r < srcR && c + 3 < srcC) ? src[(long)r * srcC + c + 3] : 0.f;
    o.x = f2bf(v0); o.y = f2bf(v1); o.z = f2bf(v2); o.w = f2bf(v3);
    *(ushort4*)(dst + e) = o;
  }
}

// ---------------- pack w1/w3 interleaved (16-row groups), padded ----------------
// wp[5632][1024]; row r: f = (r>>5)*16 + (r&15); source = w3 if bit4(r) else w1; zero if f>=2736
__global__ void pack_w13(const float* __restrict__ w1, const float* __restrict__ w3,
                         ushort* __restrict__ wp) {
  long total = (long)NPK * DM / 4;
  for (long q = (long)blockIdx.x * blockDim.x + threadIdx.x; q < total;
       q += (long)gridDim.x * blockDim.x) {
    long e = q * 4;
    int r = (int)(e >> 10);
    int c = (int)(e & 1023);
    int f = ((r >> 5) << 4) + (r & 15);
    const float* src = ((r >> 4) & 1) ? w3 : w1;
    ushort4 o;
    if (f < DFF) {
      const float4 v = *(const float4*)(src + (long)f * DM + c);
      o.x = f2bf(v.x); o.y = f2bf(v.y); o.z = f2bf(v.z); o.w = f2bf(v.w);
    } else {
      o.x = o.y = o.z = o.w = 0;
    }
    *(ushort4*)(wp + e) = o;
  }
}

// ---------------- RMSNorm (f32 in -> bf16 out) ----------------
__global__ __launch_bounds__(256) void rmsnorm_bf16(const float* __restrict__ x,
                                                    const float* __restrict__ w,
                                                    ushort* __restrict__ out) {
  long row = blockIdx.x;
  int tid = threadIdx.x;
  const float4* xr = (const float4*)(x + row * DM);
  float4 v = xr[tid];
  float ss = v.x * v.x + v.y * v.y + v.z * v.z + v.w * v.w;
#pragma unroll
  for (int m = 32; m >= 1; m >>= 1) ss += __shfl_xor(ss, m);
  __shared__ float red[4];
  if ((tid & 63) == 0) red[tid >> 6] = ss;
  __syncthreads();
  float tot = red[0] + red[1] + red[2] + red[3];
  float inv = rsqrtf(tot * (1.0f / DM) + 1e-6f);
  float4 wv = ((const float4*)w)[tid];
  ushort4 o;
  o.x = f2bf(v.x * inv * wv.x);
  o.y = f2bf(v.y * inv * wv.y);
  o.z = f2bf(v.z * inv * wv.z);
  o.w = f2bf(v.w * inv * wv.w);
  ((ushort4*)(out + row * DM))[tid] = o;
}

// ---------------- scan phase A: local per-chunk scan (in place) ----------------
__global__ __launch_bounds__(256) void scan_local(float* __restrict__ Bu,
                                                  float* __restrict__ E,
                                                  const float* __restrict__ loglam) {
  int bc = blockIdx.x;
  int b = bc / NCHUNK, c = bc % NCHUNK;
  int n = threadIdx.x;
  float lam = 1.f / (1.f + __expf(-loglam[n]));
  float h = 0.f;
  long base = ((long)b * TLEN + (long)c * CLEN) * NS + n;
#pragma unroll 4
  for (int t = 0; t < CLEN; ++t) {
    long idx = base + (long)t * NS;
    h = lam * h + Bu[idx];
    Bu[idx] = h;
  }
  E[((long)b * NCHUNK + c) * NS + n] = h;
}

// ---------------- scan phase B: chunk-carry combine ----------------
__global__ __launch_bounds__(1024) void scan_carry(const float* __restrict__ E,
                                                   float* __restrict__ C,
                                                   const float* __restrict__ loglam) {
  int tid = threadIdx.x;           // 0..1023
  int b = tid >> 8, n = tid & 255;
  float lam = 1.f / (1.f + __expf(-loglam[n]));
  float lamL = lam;
#pragma unroll
  for (int i = 0; i < 6; ++i) lamL *= lamL;   // lam^64
  float carry = 0.f;
  for (int c = 0; c < NCHUNK; ++c) {
    long idx = ((long)b * NCHUNK + c) * NS + n;
    C[idx] = carry;
    carry = lamL * carry + E[idx];
  }
}

// ---------------- scan phase C: add carry, emit bf16 hs ----------------
__global__ __launch_bounds__(256) void scan_fix(const float* __restrict__ local,
                                                const float* __restrict__ Carry,
                                                const float* __restrict__ loglam,
                                                ushort* __restrict__ hsb) {
  int bc = blockIdx.x;
  int b = bc / NCHUNK, c = bc % NCHUNK;
  int n = threadIdx.x;
  float lam = 1.f / (1.f + __expf(-loglam[n]));
  float p = Carry[((long)b * NCHUNK + c) * NS + n];
  long base = ((long)b * TLEN + (long)c * CLEN) * NS + n;
#pragma unroll 4
  for (int t = 0; t < CLEN; ++t) {
    p *= lam;
    long idx = base + (long)t * NS;
    hsb[idx] = f2bf(local[idx] + p);
  }
}

// ---------------- small bf16 NT GEMM, 128x128x32 (m97 structure) ----------------
// EPI: 0 = store f32 ; 1 = out = acc + x + Dskip*u (residual-1, N==DM)
template <int EPI>
__global__ __launch_bounds__(256, 2) void gemm_bt(
    const ushort* __restrict__ A, const ushort* __restrict__ B0,
    float* __restrict__ outF,
    const float* __restrict__ xin, const float* __restrict__ dskip,
    const ushort* __restrict__ uin, int M, int N, int K) {
  __shared__ ushort sA[128 * 32];
  __shared__ ushort sB[128 * 32];

  int tid = threadIdx.x;
  int lane = tid & 63;
  int wid = tid >> 6;
  int nbx = N >> 7;
  int by = blockIdx.x / nbx;
  int bx = blockIdx.x - by * nbx;
  long brow = (long)by << 7;
  long bcol = (long)bx << 7;

  int srow = tid >> 2;
  int scol = (tid & 3) << 3;
  const ushort* gA = A + (brow + srow) * (long)K + scol;
  const ushort* gB = B0 + (bcol + srow) * (long)K + scol;
  ushort* lA = sA + (wid << 9);
  ushort* lB = sB + (wid << 9);

  int wr = wid >> 1, wc = wid & 1;
  int fr = lane & 15;
  int fk = (lane >> 4) << 3;

  f32x4 acc0[4][4];
#pragma unroll
  for (int i = 0; i < 4; ++i)
#pragma unroll
    for (int j = 0; j < 4; ++j) acc0[i][j] = (f32x4)0.f;

  long rowq = 64 * (long)K;
  for (int kt = 0; kt < K; kt += 32) {
    __syncthreads();
    gload16(gA + kt, lA);
    gload16(gA + kt + rowq, lA + 2048);
    gload16(gB + kt, lB);
    gload16(gB + kt + rowq, lB + 2048);
    __syncthreads();

    bf16x8 a[4], b[4];
#pragma unroll
    for (int i = 0; i < 4; ++i)
      a[i] = *(const bf16x8*)(sA + ((wr * 64 + i * 16 + fr) * 32 + fk));
#pragma unroll
    for (int j = 0; j < 4; ++j)
      b[j] = *(const bf16x8*)(sB + ((wc * 64 + j * 16 + fr) * 32 + fk));
#pragma unroll
    for (int i = 0; i < 4; ++i)
#pragma unroll
      for (int j = 0; j < 4; ++j)
        acc0[i][j] = __builtin_amdgcn_mfma_f32_16x16x32_bf16(a[i], b[j], acc0[i][j], 0, 0, 0);
  }

#pragma unroll
  for (int i = 0; i < 4; ++i) {
    int rowb = wr * 64 + i * 16 + ((lane >> 4) << 2);
#pragma unroll
    for (int j = 0; j < 4; ++j) {
      long gcol = bcol + wc * 64 + j * 16 + fr;
#pragma unroll
      for (int r = 0; r < 4; ++r) {
        long grow = brow + rowb + r;
        long idx = grow * N + gcol;
        float v = acc0[i][j][r];
        if constexpr (EPI == 0) {
          outF[idx] = v;
        } else {
          outF[idx] = v + xin[idx] + dskip[gcol] * bf2f(uin[idx]);
        }
      }
    }
  }
}

// ---------------- big bf16 NT GEMM, 256x128x64, triple-buffered, counted vmcnt ----
// A [M,K] bf16; B [N,K] bf16. DUAL: N=5632 interleaved w1/w3, epilogue writes
// gv[16384][2816] = bf16(silu(gate)*val). !DUAL: outF[16384][1024] += acc.
// LDS: 3 buffers x (A 256x64 + B 128x64) bf16 = 3*24576 ushorts = 147456 B (dynamic).
// Swizzle: 16B colslot cs stored at cs^(row&7) via pre-swizzled global source;
// ds_read applies the same XOR (involution). One s_barrier per K-tile; vmcnt(6)
// keeps next tile's 6 loads in flight across the barrier (T3/T4).
template <bool DUAL>
__global__ __launch_bounds__(512, 2) void big_gemm(
    const ushort* __restrict__ A, const ushort* __restrict__ Bm,
    float* __restrict__ outF, ushort* __restrict__ outU) {
  constexpr int K = DUAL ? DM : DFFP;
  constexpr int N = DUAL ? NPK : DM;
  constexpr int NT = K / 64;
  constexpr int NBX = N / 128;
  constexpr int NWG = 64 * NBX;
  constexpr int BUFE = 24576;          // ushorts per buffer
  extern __shared__ __align__(16) char smem_raw[];
  ushort* lds = (ushort*)smem_raw;

  int tid = threadIdx.x;
  int lane = tid & 63;
  int wid = tid >> 6;

  // XCD swizzle (NWG % 8 == 0) + column-major block order: consecutive logical
  // ids share the B-panel (L2-resident) and stream A row-bands.
  int bid = blockIdx.x;
  int swz = (bid & 7) * (NWG >> 3) + (bid >> 3);
  int by = swz & 63;
  int bx = swz >> 6;
  long brow = (long)by << 8;
  long bcol = (long)bx << 7;

  // staging offsets (source pre-swizzled, LDS dest linear)
  uint aOff[4]; int aDst[4];
  uint bOff[2]; int bDst[2];
#pragma unroll
  for (int q = 0; q < 4; ++q) {
    int slot = q * 512 + tid;
    int row = slot >> 3, cs = slot & 7;
    int csx = cs ^ (row & 7);
    aOff[q] = (uint)((brow + row) * (long)K + csx * 8);
    aDst[q] = q * 4096 + wid * 512;           // wave-uniform
  }
#pragma unroll
  for (int q = 0; q < 2; ++q) {
    int slot = q * 512 + tid;
    int row = slot >> 3, cs = slot & 7;
    int csx = cs ^ (row & 7);
    bOff[q] = (uint)((bcol + row) * (long)K + csx * 8);
    bDst[q] = 16384 + q * 4096 + wid * 512;
  }

  // fragment read addresses (swizzled)
  int wrm = wid >> 1, wcn = wid & 1;
  int fr = lane & 15, fq = lane >> 4;
  int aAdr[2][4], bAdr[2][4];
#pragma unroll
  for (int kk = 0; kk < 2; ++kk)
#pragma unroll
    for (int i = 0; i < 4; ++i) {
      int row = wrm * 64 + i * 16 + fr;
      aAdr[kk][i] = row * 64 + (((kk * 4 + fq) ^ (row & 7)) << 3);
      int rowb = wcn * 64 + i * 16 + fr;
      bAdr[kk][i] = 16384 + rowb * 64 + (((kk * 4 + fq) ^ (rowb & 7)) << 3);
    }

  auto STAGE = [&](int g, int buf) {
    const ushort* Ag = A + (long)g * 64;
    const ushort* Bg = Bm + (long)g * 64;
    ushort* lb = lds + buf * BUFE;
#pragma unroll
    for (int q = 0; q < 4; ++q) gload16(Ag + aOff[q], lb + aDst[q]);
#pragma unroll
    for (int q = 0; q < 2; ++q) gload16(Bg + bOff[q], lb + bDst[q]);
  };

  f32x4 acc[4][4];
#pragma unroll
  for (int i = 0; i < 4; ++i)
#pragma unroll
    for (int j = 0; j < 4; ++j) acc[i][j] = (f32x4)0.f;

  // prologue: tiles 0,1 in flight; drain tile 0 (vmcnt leaves tile 1's 6 loads)
  STAGE(0, 0);
  STAGE(1, 1);
  asm volatile("s_waitcnt vmcnt(6)" ::: "memory");
  asm volatile("s_barrier" ::: "memory");

  int cb = 0, sb = 2;
#pragma unroll 1
  for (int g = 0; g < NT - 2; ++g) {
    const ushort* lb = lds + cb * BUFE;
    bf16x8 a[2][4], b[2][4];
#pragma unroll
    for (int kk = 0; kk < 2; ++kk)
#pragma unroll
      for (int i = 0; i < 4; ++i) {
        a[kk][i] = *(const bf16x8*)(lb + aAdr[kk][i]);
        b[kk][i] = *(const bf16x8*)(lb + bAdr[kk][i]);
      }
    STAGE(g + 2, sb);     // into buffer freed at end of iter g-1 (provable: all
                          // waves' reads of tile g-1 completed before that barrier)
#pragma unroll
    for (int kk = 0; kk < 2; ++kk)
#pragma unroll
      for (int i = 0; i < 4; ++i)
#pragma unroll
        for (int j = 0; j < 4; ++j)
          acc[i][j] = __builtin_amdgcn_mfma_f32_16x16x32_bf16(a[kk][i], b[kk][j], acc[i][j], 0, 0, 0);
    // drain tile g+1 (leave tile g+2's 6 loads flying); barrier makes it cross-wave
    asm volatile("s_waitcnt vmcnt(6)" ::: "memory");
    asm volatile("s_barrier" ::: "memory");
    cb = (cb == 2) ? 0 : cb + 1;
    sb = (sb == 2) ? 0 : sb + 1;
  }
  // iter NT-2: no staging; drain everything for the last tile
  {
    const ushort* lb = lds + cb * BUFE;
    bf16x8 a[2][4], b[2][4];
#pragma unroll
    for (int kk = 0; kk < 2; ++kk)
#pragma unroll
      for (int i = 0; i < 4; ++i) {
        a[kk][i] = *(const bf16x8*)(lb + aAdr[kk][i]);
        b[kk][i] = *(const bf16x8*)(lb + bAdr[kk][i]);
      }
#pragma unroll
    for (int kk = 0; kk < 2; ++kk)
#pragma unroll
      for (int i = 0; i < 4; ++i)
#pragma unroll
        for (int j = 0; j < 4; ++j)
          acc[i][j] = __builtin_amdgcn_mfma_f32_16x16x32_bf16(a[kk][i], b[kk][j], acc[i][j], 0, 0, 0);
    asm volatile("s_waitcnt vmcnt(0)" ::: "memory");
    asm volatile("s_barrier" ::: "memory");
    cb = (cb == 2) ? 0 : cb + 1;
  }
  // iter NT-1
  {
    const ushort* lb = lds + cb * BUFE;
    bf16x8 a[2][4], b[2][4];
#pragma unroll
    for (int kk = 0; kk < 2; ++kk)
#pragma unroll
      for (int i = 0; i < 4; ++i) {
        a[kk][i] = *(const bf16x8*)(lb + aAdr[kk][i]);
        b[kk][i] = *(const bf16x8*)(lb + bAdr[kk][i]);
      }
#pragma unroll
    for (int kk = 0; kk < 2; ++kk)
#pragma unroll
      for (int i = 0; i < 4; ++i)
#pragma unroll
        for (int j = 0; j < 4; ++j)
          acc[i][j] = __builtin_amdgcn_mfma_f32_16x16x32_bf16(a[kk][i], b[kk][j], acc[i][j], 0, 0, 0);
  }

  // epilogue (C/D: col = lane&15, row = (lane>>4)*4 + reg)
#pragma unroll
  for (int i = 0; i < 4; ++i) {
    int rowb = wrm * 64 + i * 16 + fq * 4;
    if constexpr (DUAL) {
#pragma unroll
      for (int jp = 0; jp < 2; ++jp) {
        int j = jp * 2;
        long fcol = (bcol >> 1) + wcn * 32 + jp * 16 + fr;
#pragma unroll
        for (int r = 0; r < 4; ++r) {
          long grow = brow + rowb + r;
          float gt = acc[i][j][r];
          float vl = acc[i][j + 1][r];
          float s = gt / (1.f + __expf(-gt));
          outU[grow * DFFP + fcol] = f2bf(s * vl);
        }
      }
    } else {
#pragma unroll
      for (int j = 0; j < 4; ++j) {
        long gcol = bcol + wcn * 64 + j * 16 + fr;
#pragma unroll
        for (int r = 0; r < 4; ++r) {
          long grow = brow + rowb + r;
          outF[grow * DM + gcol] += acc[i][j][r];
        }
      }
    }
  }
}

// ---------------- launch ----------------
extern "C" void kernel_launch(void* const* d_in, const int* in_sizes, int n_in,
                              void* d_out, int out_size, void* d_ws, size_t ws_size,
                              hipStream_t stream) {
  const float* x      = (const float*)d_in[0];
  const float* loglam = (const float*)d_in[1];
  const float* B_w    = (const float*)d_in[2];
  const float* C_w    = (const float*)d_in[3];
  const float* D_skip = (const float*)d_in[4];
  const float* ssm_w  = (const float*)d_in[5];
  const float* ffn_w  = (const float*)d_in[6];
  const float* w1     = (const float*)d_in[7];
  const float* w2     = (const float*)d_in[8];
  const float* w3     = (const float*)d_in[9];
  float* out = (float*)d_out;

  char* ws = (char*)d_ws;
  ushort* u_bf  = (ushort*)(ws + 0);           // 33554432
  float*  Bu    = (float*) (ws + 33554432);    // 16777216
  ushort* hs_bf = (ushort*)(ws + 50331648);    // 8388608
  float*  E     = (float*) (ws + 58720256);    // 262144
  float*  Carry = (float*) (ws + 58982400);    // 262144
  ushort* wB    = (ushort*)(ws + 59244544);    // 524288
  ushort* wC    = (ushort*)(ws + 59768832);    // 524288
  ushort* Wp    = (ushort*)(ws + 60293120);    // 11534336 (interleaved w1/w3)
  ushort* w2p   = (ushort*)(ws + 71827456);    // 5767168
  ushort* gv    = (ushort*)(ws + 77594624);    // 92274688 -> total 169869312

  constexpr int BIG_LDS = 147456;
  (void)hipFuncSetAttribute((const void*)&big_gemm<true>,
                            hipFuncAttributeMaxDynamicSharedMemorySize, BIG_LDS);
  (void)hipFuncSetAttribute((const void*)&big_gemm<false>,
                            hipFuncAttributeMaxDynamicSharedMemorySize, BIG_LDS);

  auto cvb = [](long elems) {
    long q = elems / 4;
    long b = (q + 255) / 256;
    return (int)(b > 4096 ? 4096 : b);
  };

  // weight conversion
  convert_pad<<<cvb(256L * 1024), 256, 0, stream>>>(B_w, wB, 256, 1024, 256, 1024);
  convert_pad<<<cvb(1024L * 256), 256, 0, stream>>>(C_w, wC, 1024, 256, 1024, 256);
  pack_w13<<<2048, 256, 0, stream>>>(w1, w3, Wp);
  convert_pad<<<cvb(1024L * DFFP), 256, 0, stream>>>(w2, w2p, 1024, DFF, 1024, DFFP);

  // SSM branch
  rmsnorm_bf16<<<BSZ * TLEN, 256, 0, stream>>>(x, ssm_w, u_bf);
  gemm_bt<0><<<(16384 / 128) * (NS / 128), 256, 0, stream>>>(
      u_bf, wB, Bu, nullptr, nullptr, nullptr, 16384, NS, DM);
  scan_local<<<BSZ * NCHUNK, 256, 0, stream>>>(Bu, E, loglam);
  scan_carry<<<1, 1024, 0, stream>>>(E, Carry, loglam);
  scan_fix<<<BSZ * NCHUNK, 256, 0, stream>>>(Bu, Carry, loglam, hs_bf);
  gemm_bt<1><<<(16384 / 128) * (DM / 128), 256, 0, stream>>>(
      hs_bf, wC, out, x, D_skip, u_bf, 16384, DM, NS);

  // FFN branch
  rmsnorm_bf16<<<BSZ * TLEN, 256, 0, stream>>>(out, ffn_w, u_bf);  // z reuses u buffer
  big_gemm<true><<<64 * (NPK / 128), 512, BIG_LDS, stream>>>(u_bf, Wp, nullptr, gv);
  big_gemm<false><<<64 * (DM / 128), 512, BIG_LDS, stream>>>(gv, w2p, out, nullptr);
}

// Round 4
// 561.419 us; speedup vs baseline: 1.1582x; 1.1090x over previous
//
#include <hip/hip_runtime.h>
#include <hip/hip_bf16.h>
#include <cstdint>

// Problem constants
#define BSZ   4
#define TLEN  4096
#define DM    1024
#define NS    256
#define DFF   2736
#define DFFP  2816        // padded to multiple of 128
#define NPK   5632        // interleaved w1/w3 rows (2*DFFP)
#define NCHUNK 64
#define CLEN   64         // TLEN / NCHUNK

typedef __attribute__((ext_vector_type(8))) short bf16x8;
typedef __attribute__((ext_vector_type(4))) float f32x4;

__device__ __forceinline__ float bf2f(ushort u) {
  union { unsigned int i; float f; } v; v.i = ((unsigned int)u) << 16; return v.f;
}
__device__ __forceinline__ ushort f2bf(float f) {
  union { float f; unsigned int i; } v; v.f = f;
  unsigned int r = v.i + 0x7FFFu + ((v.i >> 16) & 1u);
  return (ushort)(r >> 16);
}
__device__ __forceinline__ void gload16(const ushort* g, ushort* l) {
  __builtin_amdgcn_global_load_lds((const __attribute__((address_space(1))) void*)g,
                                   (__attribute__((address_space(3))) void*)l, 16, 0, 0);
}

// ---------------- weight convert + pad to bf16 ----------------
__global__ void convert_pad(const float* __restrict__ src, ushort* __restrict__ dst,
                            int srcR, int srcC, int dstR, int dstC) {
  long total = (long)dstR * dstC / 4;
  for (long q = (long)blockIdx.x * blockDim.x + threadIdx.x; q < total;
       q += (long)gridDim.x * blockDim.x) {
    long e = q * 4;
    int r = (int)(e / dstC);
    int c = (int)(e % dstC);
    ushort4 o;
    float v0 = (r < srcR && c + 0 < srcC) ? src[(long)r * srcC + c + 0] : 0.f;
    float v1 = (r < srcR && c + 1 < srcC) ? src[(long)r * srcC + c + 1] : 0.f;
    float v2 = (r < srcR && c + 2 < srcC) ? src[(long)r * srcC + c + 2] : 0.f;
    float v3 = (r < srcR && c + 3 < srcC) ? src[(long)r * srcC + c + 3] : 0.f;
    o.x = f2bf(v0); o.y = f2bf(v1); o.z = f2bf(v2); o.w = f2bf(v3);
    *(ushort4*)(dst + e) = o;
  }
}

// ---------------- pack w1/w3 interleaved (16-row groups), padded ----------------
__global__ void pack_w13(const float* __restrict__ w1, const float* __restrict__ w3,
                         ushort* __restrict__ wp) {
  long total = (long)NPK * DM / 4;
  for (long q = (long)blockIdx.x * blockDim.x + threadIdx.x; q < total;
       q += (long)gridDim.x * blockDim.x) {
    long e = q * 4;
    int r = (int)(e >> 10);
    int c = (int)(e & 1023);
    int f = ((r >> 5) << 4) + (r & 15);
    const float* src = ((r >> 4) & 1) ? w3 : w1;
    ushort4 o;
    if (f < DFF) {
      const float4 v = *(const float4*)(src + (long)f * DM + c);
      o.x = f2bf(v.x); o.y = f2bf(v.y); o.z = f2bf(v.z); o.w = f2bf(v.w);
    } else {
      o.x = o.y = o.z = o.w = 0;
    }
    *(ushort4*)(wp + e) = o;
  }
}

// ---------------- RMSNorm (f32 in -> bf16 out) ----------------
__global__ __launch_bounds__(256) void rmsnorm_bf16(const float* __restrict__ x,
                                                    const float* __restrict__ w,
                                                    ushort* __restrict__ out) {
  long row = blockIdx.x;
  int tid = threadIdx.x;
  const float4* xr = (const float4*)(x + row * DM);
  float4 v = xr[tid];
  float ss = v.x * v.x + v.y * v.y + v.z * v.z + v.w * v.w;
#pragma unroll
  for (int m = 32; m >= 1; m >>= 1) ss += __shfl_xor(ss, m);
  __shared__ float red[4];
  if ((tid & 63) == 0) red[tid >> 6] = ss;
  __syncthreads();
  float tot = red[0] + red[1] + red[2] + red[3];
  float inv = rsqrtf(tot * (1.0f / DM) + 1e-6f);
  float4 wv = ((const float4*)w)[tid];
  ushort4 o;
  o.x = f2bf(v.x * inv * wv.x);
  o.y = f2bf(v.y * inv * wv.y);
  o.z = f2bf(v.z * inv * wv.z);
  o.w = f2bf(v.w * inv * wv.w);
  ((ushort4*)(out + row * DM))[tid] = o;
}

// ---------------- scan phase A: local per-chunk scan (in place) ----------------
__global__ __launch_bounds__(256) void scan_local(float* __restrict__ Bu,
                                                  float* __restrict__ E,
                                                  const float* __restrict__ loglam) {
  int bc = blockIdx.x;
  int b = bc / NCHUNK, c = bc % NCHUNK;
  int n = threadIdx.x;
  float lam = 1.f / (1.f + __expf(-loglam[n]));
  float h = 0.f;
  long base = ((long)b * TLEN + (long)c * CLEN) * NS + n;
#pragma unroll 4
  for (int t = 0; t < CLEN; ++t) {
    long idx = base + (long)t * NS;
    h = lam * h + Bu[idx];
    Bu[idx] = h;
  }
  E[((long)b * NCHUNK + c) * NS + n] = h;
}

// ---------------- scan phase B: chunk-carry combine ----------------
__global__ __launch_bounds__(1024) void scan_carry(const float* __restrict__ E,
                                                   float* __restrict__ C,
                                                   const float* __restrict__ loglam) {
  int tid = threadIdx.x;
  int b = tid >> 8, n = tid & 255;
  float lam = 1.f / (1.f + __expf(-loglam[n]));
  float lamL = lam;
#pragma unroll
  for (int i = 0; i < 6; ++i) lamL *= lamL;   // lam^64
  float carry = 0.f;
  for (int c = 0; c < NCHUNK; ++c) {
    long idx = ((long)b * NCHUNK + c) * NS + n;
    C[idx] = carry;
    carry = lamL * carry + E[idx];
  }
}

// ---------------- scan phase C: add carry, emit bf16 hs ----------------
__global__ __launch_bounds__(256) void scan_fix(const float* __restrict__ local,
                                                const float* __restrict__ Carry,
                                                const float* __restrict__ loglam,
                                                ushort* __restrict__ hsb) {
  int bc = blockIdx.x;
  int b = bc / NCHUNK, c = bc % NCHUNK;
  int n = threadIdx.x;
  float lam = 1.f / (1.f + __expf(-loglam[n]));
  float p = Carry[((long)b * NCHUNK + c) * NS + n];
  long base = ((long)b * TLEN + (long)c * CLEN) * NS + n;
#pragma unroll 4
  for (int t = 0; t < CLEN; ++t) {
    p *= lam;
    long idx = base + (long)t * NS;
    hsb[idx] = f2bf(local[idx] + p);
  }
}

// ---------------- small bf16 NT GEMM, 128x128x32 (m97 structure) ----------------
// EPI: 0 = store f32 ; 1 = out = acc + x + Dskip*u (residual-1, N==DM)
template <int EPI>
__global__ __launch_bounds__(256, 2) void gemm_bt(
    const ushort* __restrict__ A, const ushort* __restrict__ B0,
    float* __restrict__ outF,
    const float* __restrict__ xin, const float* __restrict__ dskip,
    const ushort* __restrict__ uin, int M, int N, int K) {
  __shared__ ushort sA[128 * 32];
  __shared__ ushort sB[128 * 32];

  int tid = threadIdx.x;
  int lane = tid & 63;
  int wid = tid >> 6;
  int nbx = N >> 7;
  int by = blockIdx.x / nbx;
  int bx = blockIdx.x - by * nbx;
  long brow = (long)by << 7;
  long bcol = (long)bx << 7;

  int srow = tid >> 2;
  int scol = (tid & 3) << 3;
  const ushort* gA = A + (brow + srow) * (long)K + scol;
  const ushort* gB = B0 + (bcol + srow) * (long)K + scol;
  ushort* lA = sA + (wid << 9);
  ushort* lB = sB + (wid << 9);

  int wr = wid >> 1, wc = wid & 1;
  int fr = lane & 15;
  int fk = (lane >> 4) << 3;

  f32x4 acc0[4][4];
#pragma unroll
  for (int i = 0; i < 4; ++i)
#pragma unroll
    for (int j = 0; j < 4; ++j) acc0[i][j] = (f32x4)0.f;

  long rowq = 64 * (long)K;
  for (int kt = 0; kt < K; kt += 32) {
    __syncthreads();
    gload16(gA + kt, lA);
    gload16(gA + kt + rowq, lA + 2048);
    gload16(gB + kt, lB);
    gload16(gB + kt + rowq, lB + 2048);
    __syncthreads();

    bf16x8 a[4], b[4];
#pragma unroll
    for (int i = 0; i < 4; ++i)
      a[i] = *(const bf16x8*)(sA + ((wr * 64 + i * 16 + fr) * 32 + fk));
#pragma unroll
    for (int j = 0; j < 4; ++j)
      b[j] = *(const bf16x8*)(sB + ((wc * 64 + j * 16 + fr) * 32 + fk));
#pragma unroll
    for (int i = 0; i < 4; ++i)
#pragma unroll
      for (int j = 0; j < 4; ++j)
        acc0[i][j] = __builtin_amdgcn_mfma_f32_16x16x32_bf16(a[i], b[j], acc0[i][j], 0, 0, 0);
  }

#pragma unroll
  for (int i = 0; i < 4; ++i) {
    int rowb = wr * 64 + i * 16 + ((lane >> 4) << 2);
#pragma unroll
    for (int j = 0; j < 4; ++j) {
      long gcol = bcol + wc * 64 + j * 16 + fr;
#pragma unroll
      for (int r = 0; r < 4; ++r) {
        long grow = brow + rowb + r;
        long idx = grow * N + gcol;
        float v = acc0[i][j][r];
        if constexpr (EPI == 0) {
          outF[idx] = v;
        } else {
          outF[idx] = v + xin[idx] + dskip[gcol] * bf2f(uin[idx]);
        }
      }
    }
  }
}

// ---------------- big bf16 NT GEMM, 256x256x64, double-buffered, counted vmcnt ----
// A [M=16384, K] bf16; B [N, K] bf16. 512 thr = 8 waves (2 M x 4 N), wave = 128x64.
// LDS: 2 buffers x (A 256x64 + B 256x64) bf16 = 2 x 64 KiB = 131072 B (dynamic).
// Swizzle: 16B slot cs stored at cs^(row&7) (pre-swizzled global src, linear dest);
// ds_read applies the same XOR. Per K-tile: STAGE(g+1); vmcnt(8); barrier;
// ds_read+64 MFMA/wave; barrier. Tile g+1's 8 loads stay in flight across the
// whole iteration (T3/T4); buffer overwrite safety via the end-of-iter barrier.
// Supertile order: XCD chunk = 8 row-tiles x all col-tiles, row-fast (A-bands
// L2-resident per XCD, B panels read once per chunk).
template <bool DUAL>
__global__ __launch_bounds__(512, 2) void big_gemm(
    const ushort* __restrict__ A, const ushort* __restrict__ Bm,
    float* __restrict__ outF, ushort* __restrict__ outU) {
  constexpr int K = DUAL ? DM : DFFP;
  constexpr int NT = K / 64;
  constexpr int BUFE = 32768;          // ushorts per buffer (A 16384 + B 16384)
  extern __shared__ __align__(16) char smem_raw[];
  ushort* lds = (ushort*)smem_raw;

  int tid = threadIdx.x;
  int lane = tid & 63;
  int wid = tid >> 6;

  // supertile mapping: chunk (XCD) = bid&7 owns rows [chunk*8, chunk*8+8)
  int bid = blockIdx.x;
  int chunk = bid & 7;
  int w = bid >> 3;
  int rt = chunk * 8 + (w & 7);
  int ct = w >> 3;
  long brow = (long)rt << 8;
  long bcol = (long)ct << 8;

  // staging offsets (source pre-swizzled, LDS dest linear)
  uint aOff[4], bOff[4];
  int dstBase[4];
#pragma unroll
  for (int q = 0; q < 4; ++q) {
    int slot = q * 512 + tid;
    int row = slot >> 3, cs = slot & 7;
    int csx = cs ^ (row & 7);
    aOff[q] = (uint)((brow + row) * (long)K + csx * 8);
    bOff[q] = (uint)((bcol + row) * (long)K + csx * 8);
    dstBase[q] = q * 4096 + wid * 512;   // wave-uniform
  }

  int wm = wid >> 2, wn = wid & 3;        // 2 x 4 waves, wave tile 128 x 64
  int fr = lane & 15, fq = lane >> 4;
  int abase = (wm * 128 + fr) * 64;
  int bbase = 16384 + (wn * 64 + fr) * 64;
  int sl0 = ((0 * 4 + fq) ^ (fr & 7)) << 3;
  int sl1 = ((1 * 4 + fq) ^ (fr & 7)) << 3;

  f32x4 acc[8][4];
#pragma unroll
  for (int m = 0; m < 8; ++m)
#pragma unroll
    for (int n = 0; n < 4; ++n) acc[m][n] = (f32x4)0.f;

  auto STAGE = [&](int g, int buf) {
    const ushort* Ag = A + (long)g * 64;
    const ushort* Bg = Bm + (long)g * 64;
    ushort* lb = lds + buf * BUFE;
#pragma unroll
    for (int q = 0; q < 4; ++q) gload16(Ag + aOff[q], lb + dstBase[q]);
#pragma unroll
    for (int q = 0; q < 4; ++q) gload16(Bg + bOff[q], lb + 16384 + dstBase[q]);
  };

  STAGE(0, 0);
#pragma unroll 1
  for (int g = 0; g < NT; ++g) {
    if (g + 1 < NT) {
      STAGE(g + 1, (g + 1) & 1);
      asm volatile("s_waitcnt vmcnt(8)" ::: "memory");   // tile g landed; g+1 flying
    } else {
      asm volatile("s_waitcnt vmcnt(0)" ::: "memory");
    }
    asm volatile("s_barrier" ::: "memory");
    const ushort* lb = lds + (g & 1) * BUFE;
    {
      bf16x8 a[8], b[4];
#pragma unroll
      for (int m = 0; m < 8; ++m) a[m] = *(const bf16x8*)(lb + abase + m * 1024 + sl0);
#pragma unroll
      for (int n = 0; n < 4; ++n) b[n] = *(const bf16x8*)(lb + bbase + n * 1024 + sl0);
#pragma unroll
      for (int m = 0; m < 8; ++m)
#pragma unroll
        for (int n = 0; n < 4; ++n)
          acc[m][n] = __builtin_amdgcn_mfma_f32_16x16x32_bf16(a[m], b[n], acc[m][n], 0, 0, 0);
    }
    {
      bf16x8 a[8], b[4];
#pragma unroll
      for (int m = 0; m < 8; ++m) a[m] = *(const bf16x8*)(lb + abase + m * 1024 + sl1);
#pragma unroll
      for (int n = 0; n < 4; ++n) b[n] = *(const bf16x8*)(lb + bbase + n * 1024 + sl1);
#pragma unroll
      for (int m = 0; m < 8; ++m)
#pragma unroll
        for (int n = 0; n < 4; ++n)
          acc[m][n] = __builtin_amdgcn_mfma_f32_16x16x32_bf16(a[m], b[n], acc[m][n], 0, 0, 0);
    }
    asm volatile("s_barrier" ::: "memory");
  }

  // epilogue (C/D: col = lane&15, row = (lane>>4)*4 + reg)
#pragma unroll
  for (int m = 0; m < 8; ++m) {
    int rowb = wm * 128 + m * 16 + fq * 4;
    if constexpr (DUAL) {
#pragma unroll
      for (int jp = 0; jp < 2; ++jp) {
        long fcol = (bcol >> 1) + wn * 32 + jp * 16 + fr;
#pragma unroll
        for (int r = 0; r < 4; ++r) {
          long grow = brow + rowb + r;
          float gt = acc[m][2 * jp][r];
          float vl = acc[m][2 * jp + 1][r];
          float s = gt / (1.f + __expf(-gt));
          outU[grow * DFFP + fcol] = f2bf(s * vl);
        }
      }
    } else {
#pragma unroll
      for (int n = 0; n < 4; ++n) {
        long gcol = bcol + wn * 64 + n * 16 + fr;
#pragma unroll
        for (int r = 0; r < 4; ++r) {
          long grow = brow + rowb + r;
          outF[grow * DM + gcol] += acc[m][n][r];
        }
      }
    }
  }
}

// ---------------- launch ----------------
extern "C" void kernel_launch(void* const* d_in, const int* in_sizes, int n_in,
                              void* d_out, int out_size, void* d_ws, size_t ws_size,
                              hipStream_t stream) {
  const float* x      = (const float*)d_in[0];
  const float* loglam = (const float*)d_in[1];
  const float* B_w    = (const float*)d_in[2];
  const float* C_w    = (const float*)d_in[3];
  const float* D_skip = (const float*)d_in[4];
  const float* ssm_w  = (const float*)d_in[5];
  const float* ffn_w  = (const float*)d_in[6];
  const float* w1     = (const float*)d_in[7];
  const float* w2     = (const float*)d_in[8];
  const float* w3     = (const float*)d_in[9];
  float* out = (float*)d_out;

  char* ws = (char*)d_ws;
  ushort* u_bf  = (ushort*)(ws + 0);           // 33554432
  float*  Bu    = (float*) (ws + 33554432);    // 16777216
  ushort* hs_bf = (ushort*)(ws + 50331648);    // 8388608
  float*  E     = (float*) (ws + 58720256);    // 262144
  float*  Carry = (float*) (ws + 58982400);    // 262144
  ushort* wB    = (ushort*)(ws + 59244544);    // 524288
  ushort* wC    = (ushort*)(ws + 59768832);    // 524288
  ushort* Wp    = (ushort*)(ws + 60293120);    // 11534336 (interleaved w1/w3)
  ushort* w2p   = (ushort*)(ws + 71827456);    // 5767168
  ushort* gv    = (ushort*)(ws + 77594624);    // 92274688 -> total 169869312

  constexpr int BIG_LDS = 131072;
  (void)hipFuncSetAttribute((const void*)&big_gemm<true>,
                            hipFuncAttributeMaxDynamicSharedMemorySize, BIG_LDS);
  (void)hipFuncSetAttribute((const void*)&big_gemm<false>,
                            hipFuncAttributeMaxDynamicSharedMemorySize, BIG_LDS);

  auto cvb = [](long elems) {
    long q = elems / 4;
    long b = (q + 255) / 256;
    return (int)(b > 4096 ? 4096 : b);
  };

  // weight conversion
  convert_pad<<<cvb(256L * 1024), 256, 0, stream>>>(B_w, wB, 256, 1024, 256, 1024);
  convert_pad<<<cvb(1024L * 256), 256, 0, stream>>>(C_w, wC, 1024, 256, 1024, 256);
  pack_w13<<<2048, 256, 0, stream>>>(w1, w3, Wp);
  convert_pad<<<cvb(1024L * DFFP), 256, 0, stream>>>(w2, w2p, 1024, DFF, 1024, DFFP);

  // SSM branch
  rmsnorm_bf16<<<BSZ * TLEN, 256, 0, stream>>>(x, ssm_w, u_bf);
  gemm_bt<0><<<(16384 / 128) * (NS / 128), 256, 0, stream>>>(
      u_bf, wB, Bu, nullptr, nullptr, nullptr, 16384, NS, DM);
  scan_local<<<BSZ * NCHUNK, 256, 0, stream>>>(Bu, E, loglam);
  scan_carry<<<1, 1024, 0, stream>>>(E, Carry, loglam);
  scan_fix<<<BSZ * NCHUNK, 256, 0, stream>>>(Bu, Carry, loglam, hs_bf);
  gemm_bt<1><<<(16384 / 128) * (DM / 128), 256, 0, stream>>>(
      hs_bf, wC, out, x, D_skip, u_bf, 16384, DM, NS);

  // FFN branch
  rmsnorm_bf16<<<BSZ * TLEN, 256, 0, stream>>>(out, ffn_w, u_bf);  // z reuses u buffer
  big_gemm<true><<<8 * 8 * (NPK / 256), 512, BIG_LDS, stream>>>(u_bf, Wp, nullptr, gv);
  big_gemm<false><<<8 * 8 * (DM / 256), 512, BIG_LDS, stream>>>(gv, w2p, out, nullptr);
}